// Round 5
// baseline (211.022 us; speedup 1.0000x reference)
//
#include <hip/hip_runtime.h>

#define HW    3136      // 56*56
#define HW4   784       // HW / 4
#define C_INN 256
#define C_SQZ 64
#define NB    32
#define NBC   (NB * C_INN)   // 8192 (b,c) pairs

// Native clang vector type — accepted by __builtin_nontemporal_store
// (HIP's float4 is a HIP_vector_type class and is rejected).
typedef float f4 __attribute__((ext_vector_type(4)));

// ---------------------------------------------------------------------------
// Kernel 1: global average pool. One block per (b,c) pair.
// ---------------------------------------------------------------------------
__global__ __launch_bounds__(256) void se_pool(const float* __restrict__ x,
                                               float* __restrict__ s) {
    const int bc = blockIdx.x;                         // 0..8191
    const f4* xp = (const f4*)(x + (size_t)bc * HW);
    float acc = 0.0f;
    for (int i = threadIdx.x; i < HW4; i += 256) {
        f4 v = xp[i];
        acc += (v.x + v.y) + (v.z + v.w);
    }
    // wave-64 reduction
    #pragma unroll
    for (int off = 32; off > 0; off >>= 1)
        acc += __shfl_down(acc, off, 64);
    __shared__ float part[4];
    const int lane = threadIdx.x & 63;
    const int wv   = threadIdx.x >> 6;
    if (lane == 0) part[wv] = acc;
    __syncthreads();
    if (threadIdx.x == 0) {
        float t = (part[0] + part[1]) + (part[2] + part[3]);
        s[bc] = t * (1.0f / (float)HW);
    }
}

// ---------------------------------------------------------------------------
// Kernel 2: tiny MLP 256 -> 64 -> 256 + hardsigmoid. One block per batch.
// ---------------------------------------------------------------------------
__global__ __launch_bounds__(256) void se_fc(const float* __restrict__ s,
                                             const float* __restrict__ w1,
                                             const float* __restrict__ b1,
                                             const float* __restrict__ w2,
                                             const float* __restrict__ b2,
                                             float* __restrict__ scale) {
    const int b   = blockIdx.x;   // 0..31
    const int tid = threadIdx.x;  // 0..255
    __shared__ float sv[C_INN];
    __shared__ float tv[C_SQZ];

    sv[tid] = s[b * C_INN + tid];
    __syncthreads();

    if (tid < C_SQZ) {
        float acc = b1[tid];
        const float* w = w1 + tid * C_INN;   // w1[out=tid][in]
        #pragma unroll 8
        for (int c = 0; c < C_INN; ++c) acc += w[c] * sv[c];
        tv[tid] = acc;
    }
    __syncthreads();

    float acc = b2[tid];
    const float* w = w2 + tid * C_SQZ;       // w2[out=tid][in]
    #pragma unroll 8
    for (int k = 0; k < C_SQZ; ++k) acc += w[k] * tv[k];
    // Hardsigmoid: clip(x+3, 0, 6) / 6
    float h = fminf(fmaxf(acc + 3.0f, 0.0f), 6.0f) * (1.0f / 6.0f);
    scale[b * C_INN + tid] = h;
}

// ---------------------------------------------------------------------------
// Kernel 3: excite. One block per (b,c) pair; wave-uniform scale.
// Output stores are non-temporal so the 103 MB of `out` does not evict x
// from L3 (x is still needed for the remaining reads of this same kernel).
// ---------------------------------------------------------------------------
__global__ __launch_bounds__(256) void se_excite(const float* __restrict__ x,
                                                 const float* __restrict__ scale,
                                                 float* __restrict__ out) {
    const int bc = blockIdx.x;
    const float sc = scale[bc];
    const f4* xp = (const f4*)(x + (size_t)bc * HW);
    f4*       op = (f4*)(out + (size_t)bc * HW);
    for (int i = threadIdx.x; i < HW4; i += 256) {
        f4 v = xp[i];
        v.x *= sc; v.y *= sc; v.z *= sc; v.w *= sc;
        __builtin_nontemporal_store(v, op + i);
    }
}

// ---------------------------------------------------------------------------
extern "C" void kernel_launch(void* const* d_in, const int* in_sizes, int n_in,
                              void* d_out, int out_size, void* d_ws, size_t ws_size,
                              hipStream_t stream) {
    const float* x  = (const float*)d_in[0];
    const float* w1 = (const float*)d_in[1];
    const float* b1 = (const float*)d_in[2];
    const float* w2 = (const float*)d_in[3];
    const float* b2 = (const float*)d_in[4];
    float* out = (float*)d_out;

    float* s     = (float*)d_ws;            // [32*256] pooled means
    float* scale = (float*)d_ws + NBC;      // [32*256] excite scales

    se_pool<<<NBC, 256, 0, stream>>>(x, s);
    se_fc<<<NB, 256, 0, stream>>>(s, w1, b1, w2, b2, scale);
    se_excite<<<NBC, 256, 0, stream>>>(x, scale, out);
}